// Round 1
// baseline (393.972 us; speedup 1.0000x reference)
//
#include <hip/hip_runtime.h>

#define TICKS 10000
#define NSYN 9
#define OUT_CH 64

// ---------------------------------------------------------------------------
// Stage 0: zero the 9x10000 histogram (workspace is poisoned 0xAA each call).
// ---------------------------------------------------------------------------
__global__ void zero_kernel(float* __restrict__ p, int n) {
    int i = blockIdx.x * blockDim.x + threadIdx.x;
    if (i < n) p[i] = 0.0f;
}

// ---------------------------------------------------------------------------
// Stage 1: scatter events into the histogram.
// stride==1 fast path: 1 atomic per event into class hist[(min(y,2)*3+min(x,2))][t].
// generic path: direct buf[ky*3+kx][t] atomics (up to 9 per event).
// ---------------------------------------------------------------------------
__global__ __launch_bounds__(256) void scatter_kernel(
    const float* __restrict__ values,
    const int*   __restrict__ ticks,
    const int*   __restrict__ xs,
    const int*   __restrict__ ys,
    const int*   __restrict__ stride_p,
    float*       __restrict__ hist,
    int n)
{
    const int stride = stride_p[0];           // wave-uniform after first lane read
    const int n4  = n >> 2;
    const int idx = blockIdx.x * blockDim.x + threadIdx.x;
    const int gsz = gridDim.x * blockDim.x;

    const float4* __restrict__ v4 = (const float4*)values;
    const int4*   __restrict__ t4 = (const int4*)ticks;
    const int4*   __restrict__ x4 = (const int4*)xs;
    const int4*   __restrict__ y4 = (const int4*)ys;

    if (stride == 1) {
        for (int i = idx; i < n4; i += gsz) {
            float4 v = v4[i];
            int4   t = t4[i];
            int4   x = x4[i];
            int4   y = y4[i];
            atomicAdd(&hist[(min(y.x, 2) * 3 + min(x.x, 2)) * TICKS + t.x], v.x);
            atomicAdd(&hist[(min(y.y, 2) * 3 + min(x.y, 2)) * TICKS + t.y], v.y);
            atomicAdd(&hist[(min(y.z, 2) * 3 + min(x.z, 2)) * TICKS + t.z], v.z);
            atomicAdd(&hist[(min(y.w, 2) * 3 + min(x.w, 2)) * TICKS + t.w], v.w);
        }
        // scalar tail (n not multiple of 4)
        if (idx == 0) {
            for (int i = n4 << 2; i < n; ++i) {
                atomicAdd(&hist[(min(ys[i], 2) * 3 + min(xs[i], 2)) * TICKS + ticks[i]],
                          values[i]);
            }
        }
    } else {
        for (int i = idx; i < n; i += gsz) {
            float v = values[i];
            int   t = ticks[i];
            int   x = xs[i];
            int   y = ys[i];
            #pragma unroll
            for (int ky = 0; ky < 3; ++ky) {
                int oy = y - ky;
                if (oy < 0 || (oy % stride) != 0) continue;
                #pragma unroll
                for (int kx = 0; kx < 3; ++kx) {
                    int ox = x - kx;
                    if (ox < 0 || (ox % stride) != 0) continue;
                    atomicAdd(&hist[(ky * 3 + kx) * TICKS + t], v);
                }
            }
        }
    }
}

// ---------------------------------------------------------------------------
// Stage 2: suffix-sum the 3x3 classes (stride==1 path only) and broadcast to
// all 64 channels. Each thread owns one tick column t; with gridDim.y == 1 a
// thread writes every channel (safe even when hist aliases out[0:90000], since
// the 9 reads for column t happen in-thread before any write to column t).
// ---------------------------------------------------------------------------
__global__ __launch_bounds__(256) void emit_kernel(
    const float* __restrict__ hist,
    const int*   __restrict__ stride_p,
    float*       __restrict__ out)
{
    int t = blockIdx.x * blockDim.x + threadIdx.x;
    if (t >= TICKS) return;
    const int stride = stride_p[0];

    float b[NSYN];
    #pragma unroll
    for (int s = 0; s < NSYN; ++s) b[s] = hist[s * TICKS + t];

    if (stride == 1) {
        // b currently holds class hist h[cy][cx]; convert to
        // buf[ky][kx] = sum_{cy>=ky, cx>=kx} h[cy][cx]  (2D suffix sum)
        #pragma unroll
        for (int r = 0; r < 3; ++r) {          // suffix over cx within each row
            b[r * 3 + 1] += b[r * 3 + 2];
            b[r * 3 + 0] += b[r * 3 + 1];
        }
        #pragma unroll
        for (int c = 0; c < 3; ++c) {          // suffix over cy within each col
            b[3 + c] += b[6 + c];
            b[0 + c] += b[3 + c];
        }
    }

    for (int c = blockIdx.y; c < OUT_CH; c += gridDim.y) {
        #pragma unroll
        for (int s = 0; s < NSYN; ++s) {
            out[(c * NSYN + s) * TICKS + t] = b[s];
        }
    }
}

// ---------------------------------------------------------------------------
extern "C" void kernel_launch(void* const* d_in, const int* in_sizes, int n_in,
                              void* d_out, int out_size, void* d_ws, size_t ws_size,
                              hipStream_t stream) {
    const float* values   = (const float*)d_in[0];
    const int*   ticks    = (const int*)  d_in[1];
    const int*   xs       = (const int*)  d_in[2];
    const int*   ys       = (const int*)  d_in[3];
    const int*   stride_p = (const int*)  d_in[4];
    float*       out      = (float*)      d_out;
    const int n = in_sizes[0];

    const size_t hist_bytes = (size_t)NSYN * TICKS * sizeof(float);
    float* hist;
    bool hist_in_out;
    if (ws_size >= hist_bytes) {
        hist = (float*)d_ws;
        hist_in_out = false;
    } else {
        hist = out;               // reuse channel-0 region of output as scratch
        hist_in_out = true;
    }

    // Stage 0: zero hist
    {
        int nh = NSYN * TICKS;
        zero_kernel<<<(nh + 255) / 256, 256, 0, stream>>>(hist, nh);
    }

    // Stage 1: scatter (grid sized for one vec4 event-pack per thread, capped)
    {
        int n4 = (n + 3) >> 2;
        int blocks = (n4 + 255) / 256;
        if (blocks > 8192) blocks = 8192;
        if (blocks < 1) blocks = 1;
        scatter_kernel<<<blocks, 256, 0, stream>>>(values, ticks, xs, ys,
                                                   stride_p, hist, n);
    }

    // Stage 2: suffix + 64-channel broadcast
    {
        dim3 grid((TICKS + 255) / 256, hist_in_out ? 1 : 64);
        emit_kernel<<<grid, 256, 0, stream>>>(hist, stride_p, out);
    }
}

// Round 2
// 134.432 us; speedup vs baseline: 2.9306x; 2.9306x over previous
//
#include <hip/hip_runtime.h>

#define TICKS 10000
#define NSYN 9
#define OUT_CH 64

#define SCATTER_BLOCKS 256
#define SCATTER_THREADS 1024

// ---------------------------------------------------------------------------
// Stage 0: zero the 9x10000 global histogram (ws is poisoned 0xAA each call).
// ---------------------------------------------------------------------------
__global__ void zero_kernel(float* __restrict__ p, int n) {
    int i = blockIdx.x * blockDim.x + threadIdx.x;
    if (i < n) p[i] = 0.0f;
}

// ---------------------------------------------------------------------------
// Stage 1: scatter events into the 9-class histogram.
// stride==1 fast path: class = min(y,2)*3 + min(x,2). ~97% of events are
// class 8 (x>=2 && y>=2) -> LDS-private per-block histogram (40 KB), flushed
// once at the end with coalesced, phase-staggered global atomics. Rare
// classes (~3%) go straight to global atomics (low contention).
// generic-stride path: direct 9-way global atomics.
// ---------------------------------------------------------------------------
__global__ __launch_bounds__(SCATTER_THREADS) void scatter_kernel(
    const float* __restrict__ values,
    const int*   __restrict__ ticks,
    const int*   __restrict__ xs,
    const int*   __restrict__ ys,
    const int*   __restrict__ stride_p,
    float*       __restrict__ hist,
    int n)
{
    __shared__ float lhist[TICKS];            // 40 KB: class-8 private hist
    const int stride = stride_p[0];           // wave-uniform
    const int tid = threadIdx.x;

    if (stride == 1) {
        for (int j = tid; j < TICKS; j += SCATTER_THREADS) lhist[j] = 0.0f;
        __syncthreads();

        const int n4  = n >> 2;
        const int gsz = gridDim.x * SCATTER_THREADS;
        const float4* __restrict__ v4 = (const float4*)values;
        const int4*   __restrict__ t4 = (const int4*)ticks;
        const int4*   __restrict__ x4 = (const int4*)xs;
        const int4*   __restrict__ y4 = (const int4*)ys;

        for (int i = blockIdx.x * SCATTER_THREADS + tid; i < n4; i += gsz) {
            float4 v = v4[i];
            int4   t = t4[i];
            int4   x = x4[i];
            int4   y = y4[i];

            if (x.x >= 2 && y.x >= 2) atomicAdd(&lhist[t.x], v.x);
            else atomicAdd(&hist[(min(y.x, 2) * 3 + min(x.x, 2)) * TICKS + t.x], v.x);

            if (x.y >= 2 && y.y >= 2) atomicAdd(&lhist[t.y], v.y);
            else atomicAdd(&hist[(min(y.y, 2) * 3 + min(x.y, 2)) * TICKS + t.y], v.y);

            if (x.z >= 2 && y.z >= 2) atomicAdd(&lhist[t.z], v.z);
            else atomicAdd(&hist[(min(y.z, 2) * 3 + min(x.z, 2)) * TICKS + t.z], v.z);

            if (x.w >= 2 && y.w >= 2) atomicAdd(&lhist[t.w], v.w);
            else atomicAdd(&hist[(min(y.w, 2) * 3 + min(x.w, 2)) * TICKS + t.w], v.w);
        }

        // scalar tail (n not multiple of 4): straight to global (atomic-safe)
        if (blockIdx.x == 0 && tid == 0) {
            for (int i = n4 << 2; i < n; ++i) {
                atomicAdd(&hist[(min(ys[i], 2) * 3 + min(xs[i], 2)) * TICKS + ticks[i]],
                          values[i]);
            }
        }

        __syncthreads();

        // Flush class-8 LDS hist -> global, coalesced, phase-staggered so
        // blocks don't hit identical addresses in lockstep; skip empty bins.
        int phase = (blockIdx.x * 157) % TICKS;
        for (int j = tid; j < TICKS; j += SCATTER_THREADS) {
            int b = j + phase;
            if (b >= TICKS) b -= TICKS;
            float v = lhist[b];
            if (v != 0.0f) atomicAdd(&hist[8 * TICKS + b], v);
        }
    } else {
        const int gsz = gridDim.x * SCATTER_THREADS;
        for (int i = blockIdx.x * SCATTER_THREADS + tid; i < n; i += gsz) {
            float v = values[i];
            int   t = ticks[i];
            int   x = xs[i];
            int   y = ys[i];
            #pragma unroll
            for (int ky = 0; ky < 3; ++ky) {
                int oy = y - ky;
                if (oy < 0 || (oy % stride) != 0) continue;
                #pragma unroll
                for (int kx = 0; kx < 3; ++kx) {
                    int ox = x - kx;
                    if (ox < 0 || (ox % stride) != 0) continue;
                    atomicAdd(&hist[(ky * 3 + kx) * TICKS + t], v);
                }
            }
        }
    }
}

// ---------------------------------------------------------------------------
// Stage 2: suffix-sum the 3x3 classes (stride==1 only) and broadcast to all
// 64 channels. Thread owns tick column t. With gridDim.y == 1 (hist aliases
// out) one thread writes every channel; reads of column t happen before any
// write to column t, so aliasing is safe.
// ---------------------------------------------------------------------------
__global__ __launch_bounds__(256) void emit_kernel(
    const float* __restrict__ hist,
    const int*   __restrict__ stride_p,
    float*       __restrict__ out)
{
    int t = blockIdx.x * blockDim.x + threadIdx.x;
    if (t >= TICKS) return;
    const int stride = stride_p[0];

    float b[NSYN];
    #pragma unroll
    for (int s = 0; s < NSYN; ++s) b[s] = hist[s * TICKS + t];

    if (stride == 1) {
        // class hist h[cy][cx] -> buf[ky][kx] = sum_{cy>=ky, cx>=kx} h[cy][cx]
        #pragma unroll
        for (int r = 0; r < 3; ++r) {
            b[r * 3 + 1] += b[r * 3 + 2];
            b[r * 3 + 0] += b[r * 3 + 1];
        }
        #pragma unroll
        for (int c = 0; c < 3; ++c) {
            b[3 + c] += b[6 + c];
            b[0 + c] += b[3 + c];
        }
    }

    for (int c = blockIdx.y; c < OUT_CH; c += gridDim.y) {
        #pragma unroll
        for (int s = 0; s < NSYN; ++s) {
            out[(c * NSYN + s) * TICKS + t] = b[s];
        }
    }
}

// ---------------------------------------------------------------------------
extern "C" void kernel_launch(void* const* d_in, const int* in_sizes, int n_in,
                              void* d_out, int out_size, void* d_ws, size_t ws_size,
                              hipStream_t stream) {
    const float* values   = (const float*)d_in[0];
    const int*   ticks    = (const int*)  d_in[1];
    const int*   xs       = (const int*)  d_in[2];
    const int*   ys       = (const int*)  d_in[3];
    const int*   stride_p = (const int*)  d_in[4];
    float*       out      = (float*)      d_out;
    const int n = in_sizes[0];

    const size_t hist_bytes = (size_t)NSYN * TICKS * sizeof(float);
    float* hist;
    bool hist_in_out;
    if (ws_size >= hist_bytes) {
        hist = (float*)d_ws;
        hist_in_out = false;
    } else {
        hist = out;               // reuse channel-0 region of output as scratch
        hist_in_out = true;
    }

    // Stage 0: zero hist
    {
        int nh = NSYN * TICKS;
        zero_kernel<<<(nh + 255) / 256, 256, 0, stream>>>(hist, nh);
    }

    // Stage 1: scatter — 256 blocks x 1024 threads, 1 block/CU (40 KB LDS)
    scatter_kernel<<<SCATTER_BLOCKS, SCATTER_THREADS, 0, stream>>>(
        values, ticks, xs, ys, stride_p, hist, n);

    // Stage 2: suffix + 64-channel broadcast
    {
        dim3 grid((TICKS + 255) / 256, hist_in_out ? 1 : 64);
        emit_kernel<<<grid, 256, 0, stream>>>(hist, stride_p, out);
    }
}